// Round 3
// baseline (204.417 us; speedup 1.0000x reference)
//
#include <hip/hip_runtime.h>

#define N_CLASSES 101
#define TABLE_ELEMS (N_CLASSES * N_CLASSES)

// STD = 0.05 * 101 = 5.05
__global__ void ls_init_tables(float* __restrict__ p_tab,
                               float* __restrict__ s1_tab,
                               float* __restrict__ result) {
    const int t = threadIdx.x;
    if (t == 0) result[0] = 0.0f;  // d_out is poisoned 0xAA before every launch
    if (t < N_CLASSES) {
        const float std_v = 0.05f * (float)N_CLASSES;
        const float inv2s2 = 1.0f / (2.0f * std_v * std_v);
        // logits l_c = -(c-t)^2 * inv2s2, max is 0 (at c==t), so no max-shift needed
        float denom = 0.0f;
        for (int c = 0; c < N_CLASSES; ++c) {
            float d = (float)(c - t);
            denom += expf(-d * d * inv2s2);
        }
        const float L  = logf(denom);
        const float rd = 1.0f / denom;
        float s1 = 0.0f;
        for (int c = 0; c < N_CLASSES; ++c) {
            float d = (float)(c - t);
            float l = -d * d * inv2s2;
            float p = expf(l) * rd;
            p_tab[t * N_CLASSES + c] = p;
            s1 += p * (l - L);  // sum p * logp
        }
        s1_tab[t] = s1;
    }
}

__launch_bounds__(256)
__global__ void ls_kl_main(const float* __restrict__ out,
                           const int* __restrict__ target,
                           const float* __restrict__ p_tab,
                           const float* __restrict__ s1_tab,
                           float* __restrict__ result,
                           int total4) {
    __shared__ float p_lds[TABLE_ELEMS];
    __shared__ float s1_lds[N_CLASSES];
    __shared__ float wave_part[4];

    for (int i = threadIdx.x; i < TABLE_ELEMS; i += 256) p_lds[i] = p_tab[i];
    if (threadIdx.x < N_CLASSES) s1_lds[threadIdx.x] = s1_tab[threadIdx.x];
    __syncthreads();

    float acc = 0.0f;
    const int stride = gridDim.x * 256;
    for (int i4 = blockIdx.x * 256 + threadIdx.x; i4 < total4; i4 += stride) {
        const float4 v = reinterpret_cast<const float4*>(out)[i4];
        unsigned i0 = (unsigned)i4 * 4u;
        unsigned r = i0 / 101u;            // compiler emits magic-mul
        unsigned c = i0 - r * 101u;
        unsigned t = (unsigned)target[r];
        float vals[4] = {v.x, v.y, v.z, v.w};
#pragma unroll
        for (int j = 0; j < 4; ++j) {
            if (c == N_CLASSES) { c = 0u; ++r; t = (unsigned)target[r]; }
            if (c == 0u) acc += s1_lds[t];          // constant part, once per row
            acc -= p_lds[t * N_CLASSES + c] * vals[j];
            ++c;
        }
    }

    // wave (64-lane) butterfly reduce
#pragma unroll
    for (int o = 32; o > 0; o >>= 1) acc += __shfl_down(acc, o, 64);
    const int wid  = threadIdx.x >> 6;
    const int lane = threadIdx.x & 63;
    if (lane == 0) wave_part[wid] = acc;
    __syncthreads();
    if (threadIdx.x == 0) {
        float s = wave_part[0] + wave_part[1] + wave_part[2] + wave_part[3];
        atomicAdd(result, s);
    }
}

extern "C" void kernel_launch(void* const* d_in, const int* in_sizes, int n_in,
                              void* d_out, int out_size, void* d_ws, size_t ws_size,
                              hipStream_t stream) {
    const float* output = (const float*)d_in[0];
    const int*   target = (const int*)d_in[1];
    float* result = (float*)d_out;

    float* p_tab  = (float*)d_ws;             // 10201 floats
    float* s1_tab = p_tab + TABLE_ELEMS;      // 101 floats

    const int B = in_sizes[1];                // 262144
    const long long total = (long long)B * N_CLASSES;  // divisible by 4
    const int total4 = (int)(total >> 2);

    ls_init_tables<<<1, 128, 0, stream>>>(p_tab, s1_tab, result);

    int grid = (total4 + 255) / 256;
    if (grid > 2048) grid = 2048;
    ls_kl_main<<<grid, 256, 0, stream>>>(output, target, p_tab, s1_tab, result, total4);
}

// Round 8
// 191.473 us; speedup vs baseline: 1.0676x; 1.0676x over previous
//
#include <hip/hip_runtime.h>

#define N_CLASSES 101

typedef float floatx4 __attribute__((ext_vector_type(4)));  // native vector: nontemporal-builtin-compatible

// Tiny tables only: rd[t] = 1/denom(t), s1[t] = sum_c p*logp (row-constant part).
__global__ void ls_init(float* __restrict__ rd_tab,
                        float* __restrict__ s1_tab,
                        float* __restrict__ result) {
    const int t = threadIdx.x;
    if (t == 0) result[0] = 0.0f;   // d_out is re-poisoned 0xAA before every launch
    if (t < N_CLASSES) {
        const float std_v = 0.05f * (float)N_CLASSES;      // 5.05
        const float inv2s2 = 1.0f / (2.0f * std_v * std_v);
        float denom = 0.0f;
        for (int c = 0; c < N_CLASSES; ++c) {
            float d = (float)(c - t);
            denom += expf(-d * d * inv2s2);
        }
        const float L  = logf(denom);
        const float rd = 1.0f / denom;
        float s1 = 0.0f;
        for (int c = 0; c < N_CLASSES; ++c) {
            float d = (float)(c - t);
            float l = -d * d * inv2s2;
            s1 += expf(l) * rd * (l - L);                  // sum p * logp
        }
        rd_tab[t] = rd;
        s1_tab[t] = s1;
    }
}

// loss = sum_rows [ s1[t_r] - sum_c p[t_r][c]*out[r][c] ],  p computed analytically.
__launch_bounds__(256)
__global__ void ls_kl_main(const float* __restrict__ out,
                           const int* __restrict__ target,
                           const float* __restrict__ rd_tab,
                           const float* __restrict__ s1_tab,
                           float* __restrict__ result,
                           unsigned total8) {
    __shared__ float wave_part[4];
    // p = exp(-(d^2)*inv2s2) * rd = exp2(d^2 * NK2) * rd
    const float NK2 = -(1.0f / (2.0f * 5.05f * 5.05f)) * 1.44269504088896340736f;

    float acc0 = 0.0f, acc1 = 0.0f;
    const unsigned stride = gridDim.x * blockDim.x;
    for (unsigned g = blockIdx.x * blockDim.x + threadIdx.x; g < total8; g += stride) {
        // 32 B/thread of the stream, nontemporal so the 2 tiny tables stay L1-hot
        const floatx4* p4 = reinterpret_cast<const floatx4*>(out);
        const floatx4 va = __builtin_nontemporal_load(p4 + 2u * g);
        const floatx4 vb = __builtin_nontemporal_load(p4 + 2u * g + 1u);
        const float v[8] = {va.x, va.y, va.z, va.w, vb.x, vb.y, vb.z, vb.w};
        const unsigned i0 = g * 8u;
#pragma unroll
        for (int j = 0; j < 8; ++j) {
            const unsigned i = i0 + (unsigned)j;
            const unsigned r = i / 101u;            // magic-mul, independent per j -> ILP
            const unsigned c = i - r * 101u;
            const int   t = target[r];              // L1/L2 gather, near-uniform per wave
            const int   d = (int)c - t;
            const float p = exp2f((float)(d * d) * NK2) * rd_tab[t];
            const float s = (c == 0u) ? s1_tab[t] : 0.0f;   // row-constant once per row
            if (j & 1) acc1 = acc1 + s - p * v[j];
            else       acc0 = acc0 + s - p * v[j];
        }
    }

    float acc = acc0 + acc1;
#pragma unroll
    for (int o = 32; o > 0; o >>= 1) acc += __shfl_down(acc, o, 64);
    if ((threadIdx.x & 63) == 0) wave_part[threadIdx.x >> 6] = acc;
    __syncthreads();
    if (threadIdx.x == 0)
        atomicAdd(result, wave_part[0] + wave_part[1] + wave_part[2] + wave_part[3]);
}

extern "C" void kernel_launch(void* const* d_in, const int* in_sizes, int n_in,
                              void* d_out, int out_size, void* d_ws, size_t ws_size,
                              hipStream_t stream) {
    const float* output = (const float*)d_in[0];
    const int*   target = (const int*)d_in[1];
    float* result = (float*)d_out;

    float* rd_tab = (float*)d_ws;          // 101 floats
    float* s1_tab = rd_tab + N_CLASSES;    // 101 floats

    const int B = in_sizes[1];                              // 262144
    const unsigned long long total = (unsigned long long)B * N_CLASSES;
    const unsigned total8 = (unsigned)(total / 8u);         // 262144*101 divisible by 8

    ls_init<<<1, 128, 0, stream>>>(rd_tab, s1_tab, result);

    unsigned grid = (total8 + 255u) / 256u;
    if (grid > 2048u) grid = 2048u;                          // ~all-resident, 12+ iters/thread
    ls_kl_main<<<grid, 256, 0, stream>>>(output, target, rd_tab, s1_tab, result, total8);
}

// Round 10
// 179.949 us; speedup vs baseline: 1.1360x; 1.0640x over previous
//
#include <hip/hip_runtime.h>

#define N_CLASSES 101

typedef float floatx4 __attribute__((ext_vector_type(4)));

// Tiny tables: rd[t] = 1/denom(t), s1[t] = sum_c p*logp (row-constant part).
__global__ void ls_init(float* __restrict__ rd_tab,
                        float* __restrict__ s1_tab,
                        float* __restrict__ result) {
    const int t = threadIdx.x;
    if (t == 0) result[0] = 0.0f;   // d_out re-poisoned 0xAA before every launch
    if (t < N_CLASSES) {
        const float std_v = 0.05f * (float)N_CLASSES;      // 5.05
        const float inv2s2 = 1.0f / (2.0f * std_v * std_v);
        float denom = 0.0f;
        for (int c = 0; c < N_CLASSES; ++c) {
            float d = (float)(c - t);
            denom += expf(-d * d * inv2s2);
        }
        const float L  = logf(denom);
        const float rd = 1.0f / denom;
        float s1 = 0.0f;
        for (int c = 0; c < N_CLASSES; ++c) {
            float d = (float)(c - t);
            float l = -d * d * inv2s2;
            s1 += expf(l) * rd * (l - L);                  // sum p * logp
        }
        rd_tab[t] = rd;
        s1_tab[t] = s1;
    }
}

// loss = sum_rows [ s1[t_r] - sum_c p[t_r][c]*out[r][c] ], p analytic.
// Key: 8 consecutive elements span AT MOST 2 rows (row len 101 > 8), so one
// magic-div + two target/rd loads per iteration, not eight.
__launch_bounds__(256)
__global__ void ls_kl_main(const float* __restrict__ out,
                           const int* __restrict__ target,
                           const float* __restrict__ rd_tab,
                           const float* __restrict__ s1_tab,
                           float* __restrict__ result,
                           unsigned total8, int B) {
    __shared__ float wave_part[4];
    const float NK2 = -(1.0f / (2.0f * 5.05f * 5.05f)) * 1.44269504088896340736f;

    float acc0 = 0.0f, acc1 = 0.0f;
    const unsigned stride = gridDim.x * blockDim.x;
    for (unsigned g = blockIdx.x * blockDim.x + threadIdx.x; g < total8; g += stride) {
        const floatx4* p4 = reinterpret_cast<const floatx4*>(out);
        const floatx4 va = __builtin_nontemporal_load(p4 + 2u * g);
        const floatx4 vb = __builtin_nontemporal_load(p4 + 2u * g + 1u);
        const float v[8] = {va.x, va.y, va.z, va.w, vb.x, vb.y, vb.z, vb.w};

        const unsigned i0 = g * 8u;
        const unsigned r0 = i0 / 101u;               // one magic-div per 8 elems
        const unsigned c0 = i0 - r0 * 101u;
        const unsigned r1 = (r0 + 1u < (unsigned)B) ? r0 + 1u : (unsigned)B - 1u;
        const int   t0  = target[r0];
        const int   t1  = target[r1];
        const float rd0 = rd_tab[t0];
        const float rd1 = rd_tab[t1];

        // Row-constant s1 contributions, once per iteration:
        //   c0 == 0  -> this iteration starts row r0
        //   c0 >= 94 -> boundary crossing inside (starts row r0+1 at j = 101-c0)
        if (c0 == 0u)   acc0 += s1_tab[t0];
        if (c0 >= 94u)  acc1 += s1_tab[t1];

#pragma unroll
        for (int j = 0; j < 8; ++j) {
            const unsigned cj   = c0 + (unsigned)j;
            const bool     cross = cj >= 101u;
            const int      t    = cross ? t1 : t0;
            const float    rd   = cross ? rd1 : rd0;
            const int      cc   = cross ? (int)cj - 101 : (int)cj;
            const int      d    = cc - t;
            const float    p    = exp2f((float)(d * d) * NK2) * rd;
            if (j & 1) acc1 -= p * v[j];
            else       acc0 -= p * v[j];
        }
    }

    float acc = acc0 + acc1;
#pragma unroll
    for (int o = 32; o > 0; o >>= 1) acc += __shfl_down(acc, o, 64);
    if ((threadIdx.x & 63) == 0) wave_part[threadIdx.x >> 6] = acc;
    __syncthreads();
    if (threadIdx.x == 0)
        atomicAdd(result, wave_part[0] + wave_part[1] + wave_part[2] + wave_part[3]);
}

extern "C" void kernel_launch(void* const* d_in, const int* in_sizes, int n_in,
                              void* d_out, int out_size, void* d_ws, size_t ws_size,
                              hipStream_t stream) {
    const float* output = (const float*)d_in[0];
    const int*   target = (const int*)d_in[1];
    float* result = (float*)d_out;

    float* rd_tab = (float*)d_ws;          // 101 floats
    float* s1_tab = rd_tab + N_CLASSES;    // 101 floats

    const int B = in_sizes[1];                              // 262144
    const unsigned long long total = (unsigned long long)B * N_CLASSES;
    const unsigned total8 = (unsigned)(total / 8u);         // divisible by 8

    ls_init<<<1, 128, 0, stream>>>(rd_tab, s1_tab, result);

    unsigned grid = (total8 + 255u) / 256u;
    if (grid > 2048u) grid = 2048u;                          // 8 blk/CU, ~6.3 iters/thread
    ls_kl_main<<<grid, 256, 0, stream>>>(output, target, rd_tab, s1_tab, result, total8, B);
}